// Round 21
// baseline (189.684 us; speedup 1.0000x reference)
//
#include <hip/hip_runtime.h>
#include <math.h>

#define B_  16
#define H_  512
#define L_  2048
#define N2_ 32
#define NC_ 16
#define LC_ 128   // L_/NC_

typedef __attribute__((ext_vector_type(8))) short short8;
typedef __attribute__((ext_vector_type(4))) float f32x4;

__device__ __forceinline__ short f2bf(float x) {
    unsigned u = __builtin_bit_cast(unsigned, x);
    u += 0x7fffu + ((u >> 16) & 1u);           // round-to-nearest-even
    return (short)(u >> 16);
}
__device__ __forceinline__ float bf2f(unsigned short s) {
    unsigned u = ((unsigned)s) << 16;
    return __builtin_bit_cast(float, u);
}

// ---------------------------------------------------------------------------
// K0: per-(h,n) table: lambda = exp(dt*A), C' = (C_re+iC_im)*(lambda-1)/A
// ---------------------------------------------------------------------------
__global__ void k0_table(const float* __restrict__ log_dt,
                         const float* __restrict__ C_re,
                         const float* __restrict__ C_im,
                         float4* __restrict__ tab) {
    int idx = blockIdx.x * blockDim.x + threadIdx.x;   // h*N2 + n
    if (idx >= H_ * N2_) return;
    int h = idx >> 5, n = idx & 31;
    float dt = expf(log_dt[h]);
    float e  = expf(-0.5f * dt);
    float th = 3.14159265358979323846f * (float)n * dt;
    float lr = e * cosf(th), li = e * sinf(th);
    float ar = -0.5f, ai = 3.14159265358979323846f * (float)n;
    float den = ar * ar + ai * ai;
    float x = lr - 1.0f, y = li;
    float nr = (x * ar + y * ai) / den;
    float ni = (y * ar - x * ai) / den;
    float cr = C_re[idx], ci = C_im[idx];
    tab[idx] = make_float4(lr, li, cr * nr - ci * ni, cr * ni + ci * nr);
}

// ---------------------------------------------------------------------------
// T0 v2: POW[h][m][n] = lambda_n^m, closed-form per element.
// ---------------------------------------------------------------------------
__global__ void __launch_bounds__(256)
t0_pow(const float* __restrict__ log_dt, float2* __restrict__ POW) {
    int t = blockIdx.x * 256 + threadIdx.x;   // h*129*32 + m*32 + n
    if (t >= H_ * 129 * N2_) return;
    int n = t & 31;
    int m = (t >> 5) % 129;
    int h = t / (129 * N2_);
    float dt = expf(log_dt[h]);
    float fm = (float)m;
    float e  = expf(-0.5f * dt * fm);
    float th = 3.14159265358979323846f * (float)n * dt * fm;
    POW[t] = make_float2(e * cosf(th), e * sinf(th));
}

// ---------------------------------------------------------------------------
// ktab[h][m] = 2 * Re sum_n C'_n * lambda_n^m ; +D[h] at m=0 (folds D*u into
// the Toeplitz diagonal so the GELU stage never touches u).
// ---------------------------------------------------------------------------
__global__ void t_ktab(const float4* __restrict__ tab, const float2* __restrict__ POW,
                       const float* __restrict__ Dv, float* __restrict__ ktab) {
    int t = blockIdx.x * 256 + threadIdx.x;   // h*128 + m
    if (t >= H_ * 128) return;
    int h = t >> 7, m = t & 127;
    const float2* P = POW + (size_t)h * 129 * N2_ + (size_t)m * N2_;
    const float4* tb = tab + h * N2_;
    float s = 0.0f;
    for (int n = 0; n < N2_; ++n) {
        float2 p = P[n];
        float4 v = tb[n];
        s += v.z * p.x - v.w * p.y;
    }
    ktab[t] = 2.0f * s + (m == 0 ? Dv[h] : 0.0f);
}

// ---------------------------------------------------------------------------
// T1: fill Psw (pre-swizzled [h][g16][n192][8] bf16) and Vsw ([h][g8][l128][8]).
// ---------------------------------------------------------------------------
__global__ void __launch_bounds__(256)
t1_fill(const float4* __restrict__ tab, const float2* __restrict__ POW,
        const float* __restrict__ ktab, short* __restrict__ Psw,
        short* __restrict__ Vsw) {
    int t = blockIdx.x * 256 + threadIdx.x;
    int sub = t & 7;
    int rowg = t >> 3;
    int h = rowg / 320, row = rowg % 320;
    if (row < 192) {
        short8 s0, s1;
        if (row < 128) {
            int l = row;
#pragma unroll
            for (int mm = 0; mm < 8; ++mm) {
                int m0 = sub * 16 + mm, m1 = m0 + 8;
                s0[mm] = (m0 <= l) ? f2bf(ktab[h * 128 + (l - m0)]) : (short)0;
                s1[mm] = (m1 <= l) ? f2bf(ktab[h * 128 + (l - m1)]) : (short)0;
            }
        } else {
            int j = row - 128, nn = j >> 1, part = j & 1;
            const float2* P = POW + (size_t)h * 129 * N2_ + nn;
#pragma unroll
            for (int mm = 0; mm < 8; ++mm) {
                int m0 = sub * 16 + mm, m1 = m0 + 8;
                float2 p0 = P[(size_t)(127 - m0) * N2_];
                float2 p1 = P[(size_t)(127 - m1) * N2_];
                s0[mm] = f2bf(part ? p0.y : p0.x);
                s1[mm] = f2bf(part ? p1.y : p1.x);
            }
        }
        *(short8*)(Psw + ((size_t)(h * 16 + sub * 2 + 0) * 192 + row) * 8) = s0;
        *(short8*)(Psw + ((size_t)(h * 16 + sub * 2 + 1) * 192 + row) * 8) = s1;
    } else {
        int l = row - 192;
        const float2* P = POW + (size_t)h * 129 * N2_ + (size_t)(l + 1) * N2_;
        const float4* tb = tab + h * N2_;
        short8 s;
#pragma unroll
        for (int jj = 0; jj < 8; ++jj) {
            int j = sub * 8 + jj, nn = j >> 1;
            float2 p = P[nn];
            float4 cv = tb[nn];
            float re = cv.z * p.x - cv.w * p.y;
            float im = cv.z * p.y + cv.w * p.x;
            s[jj] = f2bf((j & 1) ? -2.0f * im : 2.0f * re);
        }
        *(short8*)(Vsw + ((size_t)(h * 8 + sub) * 128 + l) * 8) = s;
    }
}

// ---------------------------------------------------------------------------
// conv_mfma v4.1: ONE block per h (512 thr, 8 waves): Out(256x192) =
// U(256x128) @ P_h^T. P-fragments read DIRECTLY from global (pre-swizzled
// Psw: 16 lanes read 256B contiguous; each h read by exactly one block).
// r20 bug: P base offset was h*1536 short8 (half of the correct h*3072 =
// 24576 shorts/h). Fixed. LDS 32KB: As 16KB (conv) aliased under Ys 32KB
// (epilogue, Y staged and written in two 128-row halves, coalesced rows).
// ---------------------------------------------------------------------------
__global__ void __launch_bounds__(512)
conv_mfma(const float* __restrict__ u, const short* __restrict__ Psw,
          float* __restrict__ E, short* __restrict__ Ybuf) {
    __shared__ char smem[32768];
    short* As = (short*)smem;                  // [4][256][8] 16K (conv)
    short* Ys = (short*)smem;                  // [128][128]  32K (epilogue)
    int h = blockIdx.x;
    int tid = threadIdx.x;
    int row = tid >> 1, half = tid & 1;        // row 0..255
    int b0 = row >> 4, c0 = row & 15;
    const float* up = u + ((size_t)(b0 * H_ + h)) * L_ + (size_t)c0 * LC_ + half * 16;
    short8* AsV = (short8*)As;

    int lane = tid & 63, wave = tid >> 6;      // 8 waves
    int wm = wave >> 1, wn = wave & 1;         // 4M x 2N
    int lrow = lane & 15, lk = lane >> 4;
    const short8* AsF = (const short8*)As;
    const short8* PgF = (const short8*)Psw + (size_t)h * 3072;  // 24576 shorts/h

    f32x4 acc[4][6] = {};
    float4 fv0 = *(const float4*)(up + 0);
    float4 fv1 = *(const float4*)(up + 4);
    float4 fv2 = *(const float4*)(up + 8);
    float4 fv3 = *(const float4*)(up + 12);
#pragma unroll
    for (int ks = 0; ks < 4; ++ks) {
        // issue B-fragment loads early: latency covered by staging + barriers
        short8 bfr[6];
#pragma unroll
        for (int n = 0; n < 6; ++n)
            bfr[n] = PgF[(ks * 4 + lk) * 192 + wn * 96 + n * 16 + lrow];
        __syncthreads();
        short8 s0, s1;
        s0[0] = f2bf(fv0.x); s0[1] = f2bf(fv0.y); s0[2] = f2bf(fv0.z); s0[3] = f2bf(fv0.w);
        s0[4] = f2bf(fv1.x); s0[5] = f2bf(fv1.y); s0[6] = f2bf(fv1.z); s0[7] = f2bf(fv1.w);
        s1[0] = f2bf(fv2.x); s1[1] = f2bf(fv2.y); s1[2] = f2bf(fv2.z); s1[3] = f2bf(fv2.w);
        s1[4] = f2bf(fv3.x); s1[5] = f2bf(fv3.y); s1[6] = f2bf(fv3.z); s1[7] = f2bf(fv3.w);
        AsV[(half * 2 + 0) * 256 + row] = s0;
        AsV[(half * 2 + 1) * 256 + row] = s1;
        __syncthreads();
        if (ks < 3) {
            const float* nx = up + (ks + 1) * 32;
            fv0 = *(const float4*)(nx + 0);
            fv1 = *(const float4*)(nx + 4);
            fv2 = *(const float4*)(nx + 8);
            fv3 = *(const float4*)(nx + 12);
        }
        short8 af[4];
#pragma unroll
        for (int m = 0; m < 4; ++m)
            af[m] = AsF[lk * 256 + wm * 64 + m * 16 + lrow];
#pragma unroll
        for (int m = 0; m < 4; ++m)
#pragma unroll
            for (int n = 0; n < 6; ++n)
                acc[m][n] = __builtin_amdgcn_mfma_f32_16x16x32_bf16(
                    af[m], bfr[n], acc[m][n], 0, 0, 0);
    }

    // E fragments (cols 128..191) -> global direct (64B segments)
#pragma unroll
    for (int nf = 0; nf < 6; ++nf) {
        int col = wn * 96 + nf * 16 + lrow;
        if (col >= 128) {
#pragma unroll
            for (int mf = 0; mf < 4; ++mf) {
                int rb = wm * 64 + mf * 16 + lk * 4;
#pragma unroll
                for (int r = 0; r < 4; ++r) {
                    int Rr = rb + r, bb = Rr >> 4, cc = Rr & 15;
                    E[((size_t)(bb * H_ + h) * NC_ + cc) * 64 + (col - 128)]
                        = acc[mf][nf][r];
                }
            }
        }
    }

    // Y epilogue in two 128-row halves through the 32KB Ys stage
#pragma unroll
    for (int hp = 0; hp < 2; ++hp) {
        __syncthreads();   // As (hp=0) / previous half's reads (hp=1) done
        if ((wm >> 1) == hp) {
            int lrb = (wm & 1) * 64;     // local row base within half
#pragma unroll
            for (int nf = 0; nf < 6; ++nf) {
                int col = wn * 96 + nf * 16 + lrow;
                if (col < 128) {
#pragma unroll
                    for (int mf = 0; mf < 4; ++mf) {
                        int rb = lrb + mf * 16 + lk * 4;
#pragma unroll
                        for (int r = 0; r < 4; ++r)
                            Ys[(rb + r) * 128 + col] = f2bf(acc[mf][nf][r]);
                    }
                }
            }
        }
        __syncthreads();
        const short8* YsV = (const short8*)Ys;
#pragma unroll
        for (int it = 0; it < 4; ++it) {
            int sidx = it * 512 + tid;      // 0..2047
            int rl = sidx >> 4;             // local row 0..127
            int colq = sidx & 15;
            int Rr = hp * 128 + rl, bb = Rr >> 4, cc = Rr & 15;
            *(short8*)(Ybuf + ((size_t)(bb * H_ + h)) * L_ + (size_t)cc * LC_ + colq * 8)
                = YsV[sidx];
        }
    }
}

// ---------------------------------------------------------------------------
// K2: per-(b,h,n) serial scan over chunks (exclusive -> S at chunk start).
// ---------------------------------------------------------------------------
__global__ void k2_scan(const float* __restrict__ log_dt, float2* __restrict__ ES) {
    int t = blockIdx.x * 256 + threadIdx.x;
    if (t >= B_ * H_ * N2_) return;
    int n  = t & 31;
    int h  = (t >> 5) & (H_ - 1);
    int bh = t >> 5;
    float dt = expf(log_dt[h]);
    float e  = expf(-0.5f * dt * (float)LC_);
    float th = 3.14159265358979323846f * (float)n * dt * (float)LC_;
    float Lr = e * cosf(th), Li = e * sinf(th);
    float cr = 0.0f, ci = 0.0f;
    float2* base = ES + (size_t)bh * NC_ * N2_ + n;
#pragma unroll
    for (int c = 0; c < NC_; ++c) {
        float2 Ev = base[(size_t)c * N2_];
        base[(size_t)c * N2_] = make_float2(cr, ci);
        float ncr = fmaf(Lr, cr, fmaf(-Li, ci, Ev.x));
        float nci = fmaf(Lr, ci, fmaf(Li, cr, Ev.y));
        cr = ncr; ci = nci;
    }
}

// ---------------------------------------------------------------------------
// dcarry_mfma v2: per (h, mh): Carry(128x128) = S(128x64) @ V_h^T via MFMA.
// Carry fragments staged in LDS, then fused coalesced epilogue:
// gbf = bf16(GELU(Ybuf + carry)) in full short8 rows.
// ---------------------------------------------------------------------------
__global__ void __launch_bounds__(256)
dcarry_mfma(const float* __restrict__ ES, const short* __restrict__ Vsw,
            const short* __restrict__ Ybuf, short* __restrict__ gbf) {
    __shared__ char smem[32768];
    short* Sa = (short*)smem;             // [8][128][8] 16 KB
    short* Vb = (short*)(smem + 16384);   // [8][128][8] 16 KB
    short* Ys = (short*)smem;             // [128][128]  32 KB (post-MFMA)
    int h = blockIdx.x, mh = blockIdx.y;
    int tid = threadIdx.x;
    {
        const short8* Vg = (const short8*)(Vsw + (size_t)h * 8192);
        short8* VbV = (short8*)Vb;
#pragma unroll
        for (int j = 0; j < 4; ++j) VbV[tid + j * 256] = Vg[tid + j * 256];
    }
    int row = tid >> 1, half = tid & 1;
    int R = mh * 128 + row, b = R >> 4, c = R & 15;
    {
        const float* sp = ES + ((size_t)(b * H_ + h) * NC_ + c) * 64 + half * 32;
        short8* SaV = (short8*)Sa;
#pragma unroll
        for (int gg = 0; gg < 4; ++gg) {
            float4 f0 = *(const float4*)(sp + gg * 8);
            float4 f1 = *(const float4*)(sp + gg * 8 + 4);
            short8 s;
            s[0] = f2bf(f0.x); s[1] = f2bf(f0.y); s[2] = f2bf(f0.z); s[3] = f2bf(f0.w);
            s[4] = f2bf(f1.x); s[5] = f2bf(f1.y); s[6] = f2bf(f1.z); s[7] = f2bf(f1.w);
            SaV[(half * 4 + gg) * 128 + row] = s;
        }
    }
    __syncthreads();
    int lane = tid & 63, wave = tid >> 6;
    int wm = wave >> 1, wn = wave & 1;
    int lrow = lane & 15, lk = lane >> 4;
    const short8* SaF = (const short8*)Sa;
    const short8* VbF = (const short8*)Vb;
    f32x4 acc[4][4] = {};
#pragma unroll
    for (int ks = 0; ks < 2; ++ks) {
        int g = ks * 4 + lk;
        short8 af[4], bf[4];
#pragma unroll
        for (int m = 0; m < 4; ++m)
            af[m] = SaF[g * 128 + wm * 64 + m * 16 + lrow];
#pragma unroll
        for (int n = 0; n < 4; ++n)
            bf[n] = VbF[g * 128 + wn * 64 + n * 16 + lrow];
#pragma unroll
        for (int m = 0; m < 4; ++m)
#pragma unroll
            for (int n = 0; n < 4; ++n)
                acc[m][n] = __builtin_amdgcn_mfma_f32_16x16x32_bf16(
                    af[m], bf[n], acc[m][n], 0, 0, 0);
    }
    __syncthreads();   // Sa/Vb reads done -> reuse as Ys

#pragma unroll
    for (int nf = 0; nf < 4; ++nf) {
        int l = wn * 64 + nf * 16 + lrow;
#pragma unroll
        for (int mf = 0; mf < 4; ++mf) {
            int rb = wm * 64 + mf * 16 + lk * 4;
#pragma unroll
            for (int r = 0; r < 4; ++r)
                Ys[(rb + r) * 128 + l] = f2bf(acc[mf][nf][r]);
        }
    }
    __syncthreads();

    const short8* YsV = (const short8*)Ys;
#pragma unroll
    for (int it = 0; it < 8; ++it) {
        int sidx = it * 256 + tid;          // 0..2047
        int rr = sidx >> 4;                 // local row 0..127
        int colq = sidx & 15;
        int Rr = mh * 128 + rr, bb = Rr >> 4, cc = Rr & 15;
        size_t gaddr = ((size_t)(bb * H_ + h)) * L_ + (size_t)cc * LC_ + colq * 8;
        short8 yv = *(const short8*)(Ybuf + gaddr);
        short8 cv = YsV[sidx];
        short8 o;
#pragma unroll
        for (int j = 0; j < 8; ++j) {
            float y = bf2f((unsigned short)yv[j]) + bf2f((unsigned short)cv[j]);
            o[j] = f2bf(0.5f * y * (1.0f + erff(y * 0.70710678118654752f)));
        }
        *(short8*)(gbf + gaddr) = o;
    }
}

// ---------------------------------------------------------------------------
// W transpose + f32->bf16: Wt[n][k] = bf16(W[k][n])
// ---------------------------------------------------------------------------
__global__ void __launch_bounds__(256)
wtrans(const float* __restrict__ W, short* __restrict__ Wt, int K, int N) {
    __shared__ short tile[32][33];
    int bk = blockIdx.x * 32, bn = blockIdx.y * 32;
    int tx = threadIdx.x & 31, ty = threadIdx.x >> 5;   // ty 0..7
#pragma unroll
    for (int i = 0; i < 4; ++i)
        tile[ty + i * 8][tx] = f2bf(W[(size_t)(bk + ty + i * 8) * N + bn + tx]);
    __syncthreads();
#pragma unroll
    for (int i = 0; i < 4; ++i)
        Wt[(size_t)(bn + ty + i * 8) * K + bk + tx] = tile[tx][ty + i * 8];
}

// ---------------------------------------------------------------------------
// bf16 MFMA GEMM v5+T5 (8 waves / 512 thr / 128x128 tile, dbuf LDS, one
// barrier per K-step, s_setprio(1) around MFMA clusters).
// Grid dim3(M/128,N/128): XCD = row-panel%8 -> A-panel L2 locality.
// ---------------------------------------------------------------------------
template<bool TANH, bool OUTBF>
__global__ void __launch_bounds__(512)
gemm_mfma(const short* __restrict__ A, const short* __restrict__ Bt,
          const float* __restrict__ bias, void* __restrict__ Cout,
          int M, int N, int K) {
    __shared__ short As[2][128 * 36];
    __shared__ short Bs[2][128 * 36];
    int tid  = threadIdx.x;
    int lane = tid & 63;
    int wave = tid >> 6;                 // 0..7
    int wm = wave >> 2, wn = wave & 3;   // 2M x 4N
    int lrow = lane & 15, kblk = lane >> 4;
    int row0 = blockIdx.x * 128, col0 = blockIdx.y * 128;

    int srow = tid >> 2;            // 0..127
    int sk   = (tid & 3) * 8;       // k offset (shorts)
    const short* Ag = A  + (size_t)(row0 + srow) * K + sk;
    const short* Bg = Bt + (size_t)(col0 + srow) * K + sk;
    int si = srow * 36 + sk;

    f32x4 acc[4][2] = {};
    const int NT = K >> 5;          // 64 (GEMM1) / 32 (GEMM2) — even

    short8 pa = *(const short8*)(Ag),      pb = *(const short8*)(Bg);
    *(short8*)&As[0][si] = pa;
    *(short8*)&Bs[0][si] = pb;
    short8 qa = *(const short8*)(Ag + 32), qb = *(const short8*)(Bg + 32);
    __syncthreads();

    for (int t = 0; t < NT; t += 2) {
        if (t + 2 < NT) {
            int ko = (t + 2) << 5;
            pa = *(const short8*)(Ag + ko);
            pb = *(const short8*)(Bg + ko);
        }
        {
            short8 af[4], bf[2];
#pragma unroll
            for (int m = 0; m < 4; ++m)
                af[m] = *(const short8*)&As[0][(wm * 64 + m * 16 + lrow) * 36 + kblk * 8];
#pragma unroll
            for (int n = 0; n < 2; ++n)
                bf[n] = *(const short8*)&Bs[0][(wn * 32 + n * 16 + lrow) * 36 + kblk * 8];
            __builtin_amdgcn_s_setprio(1);
#pragma unroll
            for (int m = 0; m < 4; ++m)
#pragma unroll
                for (int n = 0; n < 2; ++n)
                    acc[m][n] = __builtin_amdgcn_mfma_f32_16x16x32_bf16(
                        af[m], bf[n], acc[m][n], 0, 0, 0);
            __builtin_amdgcn_s_setprio(0);
        }
        *(short8*)&As[1][si] = qa;
        *(short8*)&Bs[1][si] = qb;
        __syncthreads();

        if (t + 3 < NT) {
            int ko = (t + 3) << 5;
            qa = *(const short8*)(Ag + ko);
            qb = *(const short8*)(Bg + ko);
        }
        {
            short8 af[4], bf[2];
#pragma unroll
            for (int m = 0; m < 4; ++m)
                af[m] = *(const short8*)&As[1][(wm * 64 + m * 16 + lrow) * 36 + kblk * 8];
#pragma unroll
            for (int n = 0; n < 2; ++n)
                bf[n] = *(const short8*)&Bs[1][(wn * 32 + n * 16 + lrow) * 36 + kblk * 8];
            __builtin_amdgcn_s_setprio(1);
#pragma unroll
            for (int m = 0; m < 4; ++m)
#pragma unroll
                for (int n = 0; n < 2; ++n)
                    acc[m][n] = __builtin_amdgcn_mfma_f32_16x16x32_bf16(
                        af[m], bf[n], acc[m][n], 0, 0, 0);
            __builtin_amdgcn_s_setprio(0);
        }
        if (t + 2 < NT) {
            *(short8*)&As[0][si] = pa;
            *(short8*)&Bs[0][si] = pb;
        }
        __syncthreads();
    }

    // epilogue: C/D layout col=lane&15, row=(lane>>4)*4+reg
#pragma unroll
    for (int n = 0; n < 2; ++n) {
        int col = col0 + wn * 32 + n * 16 + lrow;
        float bb = bias[col];
#pragma unroll
        for (int m = 0; m < 4; ++m) {
            int rowb = row0 + wm * 64 + m * 16 + kblk * 4;
#pragma unroll
            for (int r = 0; r < 4; ++r) {
                float v = acc[m][n][r] + bb;
                if (TANH) v = tanhf(v);
                if (OUTBF) ((short*)Cout)[(size_t)(rowb + r) * N + col] = f2bf(v);
                else       ((float*)Cout)[(size_t)(rowb + r) * N + col] = v;
            }
        }
    }
}

// ---------------------------------------------------------------------------
extern "C" void kernel_launch(void* const* d_in, const int* in_sizes, int n_in,
                              void* d_out, int out_size, void* d_ws, size_t ws_size,
                              hipStream_t stream) {
    const float* u     = (const float*)d_in[0];
    const float* D     = (const float*)d_in[1];
    const float* logdt = (const float*)d_in[2];
    const float* C_re  = (const float*)d_in[3];
    const float* C_im  = (const float*)d_in[4];
    const float* W1    = (const float*)d_in[5];
    const float* b1    = (const float*)d_in[6];
    const float* W2    = (const float*)d_in[7];
    const float* b2    = (const float*)d_in[8];
    float* out = (float*)d_out;

    char* p = (char*)d_ws;
    float4* tab = (float4*)p;            p += 262144;      // H*N2*16
    char* regionA = p;                   p += 33554432;    // POW+ktab, later Ybuf
    float2* POW  = (float2*)regionA;                       // 512*129*32*8
    float*  ktab = (float*)(regionA + 16908288);           // 512*128*4
    short*  Ybuf = (short*)regionA;                        // B*H*L*2 = 32 MB (b,h,l)
    short* Psw = (short*)p;              p += 25165824;    // 512*192*128*2
    short* Vsw = (short*)p;              p += 8388608;     // 512*128*64*2
    float* E   = (float*)p;              p += 33554432;    // 8192*16*64*4
    short* gbf = (short*)p;              p += 33554432;    // B*H*L*2
    short* tb  = (short*)p;              p += 16777216;    // 8192*1024*2
    short* w1t = (short*)p;              p += 4194304;
    short* w2t = (short*)p;

    k0_table<<<H_ * N2_ / 256, 256, 0, stream>>>(logdt, C_re, C_im, tab);
    t0_pow  <<<H_ * 129 * N2_ / 256, 256, 0, stream>>>(logdt, POW);
    t_ktab  <<<H_ * 128 / 256, 256, 0, stream>>>(tab, POW, D, ktab);
    t1_fill <<<H_ * 320 * 8 / 256, 256, 0, stream>>>(tab, POW, ktab, Psw, Vsw);
    wtrans  <<<dim3(L_ / 32, 2 * H_ / 32), 256, 0, stream>>>(W1, w1t, L_, 2 * H_);
    wtrans  <<<dim3(2 * H_ / 32, H_ / 32), 256, 0, stream>>>(W2, w2t, 2 * H_, H_);

    conv_mfma  <<<H_, 512, 0, stream>>>(u, Psw, E, Ybuf);
    k2_scan    <<<B_ * H_ * N2_ / 256, 256, 0, stream>>>(logdt, (float2*)E);
    dcarry_mfma<<<dim3(H_, 2), 256, 0, stream>>>(E, Vsw, Ybuf, gbf);

    gemm_mfma<true, true ><<<dim3(B_ * H_ / 128, 2 * H_ / 128), 512, 0, stream>>>(
        gbf, w1t, b1, tb, B_ * H_, 2 * H_, L_);
    gemm_mfma<false, false><<<dim3(B_ * H_ / 128, H_ / 128), 512, 0, stream>>>(
        tb, w2t, b2, out, B_ * H_, H_, 2 * H_);
}

// Round 23
// 185.217 us; speedup vs baseline: 1.0241x; 1.0241x over previous
//
#include <hip/hip_runtime.h>
#include <math.h>

#define B_  16
#define H_  512
#define L_  2048
#define N2_ 32
#define NC_ 16
#define LC_ 128   // L_/NC_

typedef __attribute__((ext_vector_type(8))) short short8;
typedef __attribute__((ext_vector_type(4))) float f32x4;

__device__ __forceinline__ short f2bf(float x) {
    unsigned u = __builtin_bit_cast(unsigned, x);
    u += 0x7fffu + ((u >> 16) & 1u);           // round-to-nearest-even
    return (short)(u >> 16);
}
__device__ __forceinline__ float bf2f(unsigned short s) {
    unsigned u = ((unsigned)s) << 16;
    return __builtin_bit_cast(float, u);
}

// ---------------------------------------------------------------------------
// prolog: merged independent prologue kernels (block-range dispatch):
//   [0,64)        k0_table : tab[h*N2+n] = {lambda, C'}
//   [64,8320)     t0_pow   : POW[h][m][n] = lambda^m (closed form)
//   [8320,10368)  wtrans W1 -> w1t (bf16, transposed)
//   [10368,10880) wtrans W2 -> w2t
// Branch is block-uniform; __syncthreads inside wtrans branch is legal.
// ---------------------------------------------------------------------------
__device__ __forceinline__ void wtrans_body(const float* __restrict__ W,
                                            short* __restrict__ Wt,
                                            int K, int N, int bk, int bn,
                                            short (*tile)[33]) {
    int tx = threadIdx.x & 31, ty = threadIdx.x >> 5;   // ty 0..7
#pragma unroll
    for (int i = 0; i < 4; ++i)
        tile[ty + i * 8][tx] = f2bf(W[(size_t)(bk + ty + i * 8) * N + bn + tx]);
    __syncthreads();
#pragma unroll
    for (int i = 0; i < 4; ++i)
        Wt[(size_t)(bn + ty + i * 8) * K + bk + tx] = tile[tx][ty + i * 8];
}

__global__ void __launch_bounds__(256)
prolog(const float* __restrict__ log_dt, const float* __restrict__ C_re,
       const float* __restrict__ C_im, const float* __restrict__ W1,
       const float* __restrict__ W2, float4* __restrict__ tab,
       float2* __restrict__ POW, short* __restrict__ w1t,
       short* __restrict__ w2t) {
    __shared__ short tile[32][33];
    int bid = blockIdx.x;
    if (bid < 64) {
        // k0_table: idx = h*N2 + n  (64*256 = H*N2 exactly)
        int idx = bid * 256 + threadIdx.x;
        int h = idx >> 5, n = idx & 31;
        float dt = expf(log_dt[h]);
        float e  = expf(-0.5f * dt);
        float th = 3.14159265358979323846f * (float)n * dt;
        float lr = e * cosf(th), li = e * sinf(th);
        float ar = -0.5f, ai = 3.14159265358979323846f * (float)n;
        float den = ar * ar + ai * ai;
        float x = lr - 1.0f, y = li;
        float nr = (x * ar + y * ai) / den;
        float ni = (y * ar - x * ai) / den;
        float cr = C_re[idx], ci = C_im[idx];
        tab[idx] = make_float4(lr, li, cr * nr - ci * ni, cr * ni + ci * nr);
    } else if (bid < 64 + 8256) {
        // t0_pow: t = h*129*32 + m*32 + n  (8256*256 = H*129*32 exactly)
        int t = (bid - 64) * 256 + threadIdx.x;
        int n = t & 31;
        int m = (t >> 5) % 129;
        int h = t / (129 * N2_);
        float dt = expf(log_dt[h]);
        float fm = (float)m;
        float e  = expf(-0.5f * dt * fm);
        float th = 3.14159265358979323846f * (float)n * dt * fm;
        POW[t] = make_float2(e * cosf(th), e * sinf(th));
    } else if (bid < 64 + 8256 + 2048) {
        // wtrans W1: K=L(2048), N=2H(1024); grid was dim3(64, 32)
        int b2 = bid - 8320;
        wtrans_body(W1, w1t, L_, 2 * H_, (b2 & 63) * 32, (b2 >> 6) * 32, tile);
    } else {
        // wtrans W2: K=2H(1024), N=H(512); grid was dim3(32, 16)
        int b2 = bid - 10368;
        wtrans_body(W2, w2t, 2 * H_, H_, (b2 & 31) * 32, (b2 >> 5) * 32, tile);
    }
}

// ---------------------------------------------------------------------------
// ktab[h][m] = 2 * Re sum_n C'_n * lambda_n^m ; +D[h] at m=0 (folds D*u into
// the Toeplitz diagonal so the GELU stage never touches u).
// ---------------------------------------------------------------------------
__global__ void t_ktab(const float4* __restrict__ tab, const float2* __restrict__ POW,
                       const float* __restrict__ Dv, float* __restrict__ ktab) {
    int t = blockIdx.x * 256 + threadIdx.x;   // h*128 + m
    if (t >= H_ * 128) return;
    int h = t >> 7, m = t & 127;
    const float2* P = POW + (size_t)h * 129 * N2_ + (size_t)m * N2_;
    const float4* tb = tab + h * N2_;
    float s = 0.0f;
    for (int n = 0; n < N2_; ++n) {
        float2 p = P[n];
        float4 v = tb[n];
        s += v.z * p.x - v.w * p.y;
    }
    ktab[t] = 2.0f * s + (m == 0 ? Dv[h] : 0.0f);
}

// ---------------------------------------------------------------------------
// T1: fill Psw (pre-swizzled [h][g16][n192][8] bf16) and Vsw ([h][g8][l128][8]).
// ---------------------------------------------------------------------------
__global__ void __launch_bounds__(256)
t1_fill(const float4* __restrict__ tab, const float2* __restrict__ POW,
        const float* __restrict__ ktab, short* __restrict__ Psw,
        short* __restrict__ Vsw) {
    int t = blockIdx.x * 256 + threadIdx.x;
    int sub = t & 7;
    int rowg = t >> 3;
    int h = rowg / 320, row = rowg % 320;
    if (row < 192) {
        short8 s0, s1;
        if (row < 128) {
            int l = row;
#pragma unroll
            for (int mm = 0; mm < 8; ++mm) {
                int m0 = sub * 16 + mm, m1 = m0 + 8;
                s0[mm] = (m0 <= l) ? f2bf(ktab[h * 128 + (l - m0)]) : (short)0;
                s1[mm] = (m1 <= l) ? f2bf(ktab[h * 128 + (l - m1)]) : (short)0;
            }
        } else {
            int j = row - 128, nn = j >> 1, part = j & 1;
            const float2* P = POW + (size_t)h * 129 * N2_ + nn;
#pragma unroll
            for (int mm = 0; mm < 8; ++mm) {
                int m0 = sub * 16 + mm, m1 = m0 + 8;
                float2 p0 = P[(size_t)(127 - m0) * N2_];
                float2 p1 = P[(size_t)(127 - m1) * N2_];
                s0[mm] = f2bf(part ? p0.y : p0.x);
                s1[mm] = f2bf(part ? p1.y : p1.x);
            }
        }
        *(short8*)(Psw + ((size_t)(h * 16 + sub * 2 + 0) * 192 + row) * 8) = s0;
        *(short8*)(Psw + ((size_t)(h * 16 + sub * 2 + 1) * 192 + row) * 8) = s1;
    } else {
        int l = row - 192;
        const float2* P = POW + (size_t)h * 129 * N2_ + (size_t)(l + 1) * N2_;
        const float4* tb = tab + h * N2_;
        short8 s;
#pragma unroll
        for (int jj = 0; jj < 8; ++jj) {
            int j = sub * 8 + jj, nn = j >> 1;
            float2 p = P[nn];
            float4 cv = tb[nn];
            float re = cv.z * p.x - cv.w * p.y;
            float im = cv.z * p.y + cv.w * p.x;
            s[jj] = f2bf((j & 1) ? -2.0f * im : 2.0f * re);
        }
        *(short8*)(Vsw + ((size_t)(h * 8 + sub) * 128 + l) * 8) = s;
    }
}

// ---------------------------------------------------------------------------
// conv_mfma v4.1: ONE block per h (512 thr, 8 waves): Out(256x192) =
// U(256x128) @ P_h^T. P-fragments read DIRECTLY from global.
// LDS 32KB: As 16KB (conv) aliased under Ys 32KB (epilogue two halves).
// ---------------------------------------------------------------------------
__global__ void __launch_bounds__(512)
conv_mfma(const float* __restrict__ u, const short* __restrict__ Psw,
          float* __restrict__ E, short* __restrict__ Ybuf) {
    __shared__ char smem[32768];
    short* As = (short*)smem;                  // [4][256][8] 16K (conv)
    short* Ys = (short*)smem;                  // [128][128]  32K (epilogue)
    int h = blockIdx.x;
    int tid = threadIdx.x;
    int row = tid >> 1, half = tid & 1;        // row 0..255
    int b0 = row >> 4, c0 = row & 15;
    const float* up = u + ((size_t)(b0 * H_ + h)) * L_ + (size_t)c0 * LC_ + half * 16;
    short8* AsV = (short8*)As;

    int lane = tid & 63, wave = tid >> 6;      // 8 waves
    int wm = wave >> 1, wn = wave & 1;         // 4M x 2N
    int lrow = lane & 15, lk = lane >> 4;
    const short8* AsF = (const short8*)As;
    const short8* PgF = (const short8*)Psw + (size_t)h * 3072;  // 24576 shorts/h

    f32x4 acc[4][6] = {};
    float4 fv0 = *(const float4*)(up + 0);
    float4 fv1 = *(const float4*)(up + 4);
    float4 fv2 = *(const float4*)(up + 8);
    float4 fv3 = *(const float4*)(up + 12);
#pragma unroll
    for (int ks = 0; ks < 4; ++ks) {
        short8 bfr[6];
#pragma unroll
        for (int n = 0; n < 6; ++n)
            bfr[n] = PgF[(ks * 4 + lk) * 192 + wn * 96 + n * 16 + lrow];
        __syncthreads();
        short8 s0, s1;
        s0[0] = f2bf(fv0.x); s0[1] = f2bf(fv0.y); s0[2] = f2bf(fv0.z); s0[3] = f2bf(fv0.w);
        s0[4] = f2bf(fv1.x); s0[5] = f2bf(fv1.y); s0[6] = f2bf(fv1.z); s0[7] = f2bf(fv1.w);
        s1[0] = f2bf(fv2.x); s1[1] = f2bf(fv2.y); s1[2] = f2bf(fv2.z); s1[3] = f2bf(fv2.w);
        s1[4] = f2bf(fv3.x); s1[5] = f2bf(fv3.y); s1[6] = f2bf(fv3.z); s1[7] = f2bf(fv3.w);
        AsV[(half * 2 + 0) * 256 + row] = s0;
        AsV[(half * 2 + 1) * 256 + row] = s1;
        __syncthreads();
        if (ks < 3) {
            const float* nx = up + (ks + 1) * 32;
            fv0 = *(const float4*)(nx + 0);
            fv1 = *(const float4*)(nx + 4);
            fv2 = *(const float4*)(nx + 8);
            fv3 = *(const float4*)(nx + 12);
        }
        short8 af[4];
#pragma unroll
        for (int m = 0; m < 4; ++m)
            af[m] = AsF[lk * 256 + wm * 64 + m * 16 + lrow];
#pragma unroll
        for (int m = 0; m < 4; ++m)
#pragma unroll
            for (int n = 0; n < 6; ++n)
                acc[m][n] = __builtin_amdgcn_mfma_f32_16x16x32_bf16(
                    af[m], bfr[n], acc[m][n], 0, 0, 0);
    }

    // E fragments (cols 128..191) -> global direct (64B segments)
#pragma unroll
    for (int nf = 0; nf < 6; ++nf) {
        int col = wn * 96 + nf * 16 + lrow;
        if (col >= 128) {
#pragma unroll
            for (int mf = 0; mf < 4; ++mf) {
                int rb = wm * 64 + mf * 16 + lk * 4;
#pragma unroll
                for (int r = 0; r < 4; ++r) {
                    int Rr = rb + r, bb = Rr >> 4, cc = Rr & 15;
                    E[((size_t)(bb * H_ + h) * NC_ + cc) * 64 + (col - 128)]
                        = acc[mf][nf][r];
                }
            }
        }
    }

    // Y epilogue in two 128-row halves through the 32KB Ys stage
#pragma unroll
    for (int hp = 0; hp < 2; ++hp) {
        __syncthreads();   // As (hp=0) / previous half's reads (hp=1) done
        if ((wm >> 1) == hp) {
            int lrb = (wm & 1) * 64;     // local row base within half
#pragma unroll
            for (int nf = 0; nf < 6; ++nf) {
                int col = wn * 96 + nf * 16 + lrow;
                if (col < 128) {
#pragma unroll
                    for (int mf = 0; mf < 4; ++mf) {
                        int rb = lrb + mf * 16 + lk * 4;
#pragma unroll
                        for (int r = 0; r < 4; ++r)
                            Ys[(rb + r) * 128 + col] = f2bf(acc[mf][nf][r]);
                    }
                }
            }
        }
        __syncthreads();
        const short8* YsV = (const short8*)Ys;
#pragma unroll
        for (int it = 0; it < 4; ++it) {
            int sidx = it * 512 + tid;      // 0..2047
            int rl = sidx >> 4;             // local row 0..127
            int colq = sidx & 15;
            int Rr = hp * 128 + rl, bb = Rr >> 4, cc = Rr & 15;
            *(short8*)(Ybuf + ((size_t)(bb * H_ + h)) * L_ + (size_t)cc * LC_ + colq * 8)
                = YsV[sidx];
        }
    }
}

// ---------------------------------------------------------------------------
// K2: per-(b,h,n) serial scan over chunks (exclusive -> S at chunk start).
// ---------------------------------------------------------------------------
__global__ void k2_scan(const float* __restrict__ log_dt, float2* __restrict__ ES) {
    int t = blockIdx.x * 256 + threadIdx.x;
    if (t >= B_ * H_ * N2_) return;
    int n  = t & 31;
    int h  = (t >> 5) & (H_ - 1);
    int bh = t >> 5;
    float dt = expf(log_dt[h]);
    float e  = expf(-0.5f * dt * (float)LC_);
    float th = 3.14159265358979323846f * (float)n * dt * (float)LC_;
    float Lr = e * cosf(th), Li = e * sinf(th);
    float cr = 0.0f, ci = 0.0f;
    float2* base = ES + (size_t)bh * NC_ * N2_ + n;
#pragma unroll
    for (int c = 0; c < NC_; ++c) {
        float2 Ev = base[(size_t)c * N2_];
        base[(size_t)c * N2_] = make_float2(cr, ci);
        float ncr = fmaf(Lr, cr, fmaf(-Li, ci, Ev.x));
        float nci = fmaf(Lr, ci, fmaf(Li, cr, Ev.y));
        cr = ncr; ci = nci;
    }
}

// ---------------------------------------------------------------------------
// dcarry_mfma v2: per (h, mh): Carry(128x128) = S(128x64) @ V_h^T via MFMA.
// Carry fragments staged in LDS, then fused coalesced epilogue:
// gbf = bf16(GELU(Ybuf + carry)) in full short8 rows.
// ---------------------------------------------------------------------------
__global__ void __launch_bounds__(256)
dcarry_mfma(const float* __restrict__ ES, const short* __restrict__ Vsw,
            const short* __restrict__ Ybuf, short* __restrict__ gbf) {
    __shared__ char smem[32768];
    short* Sa = (short*)smem;             // [8][128][8] 16 KB
    short* Vb = (short*)(smem + 16384);   // [8][128][8] 16 KB
    short* Ys = (short*)smem;             // [128][128]  32 KB (post-MFMA)
    int h = blockIdx.x, mh = blockIdx.y;
    int tid = threadIdx.x;
    {
        const short8* Vg = (const short8*)(Vsw + (size_t)h * 8192);
        short8* VbV = (short8*)Vb;
#pragma unroll
        for (int j = 0; j < 4; ++j) VbV[tid + j * 256] = Vg[tid + j * 256];
    }
    int row = tid >> 1, half = tid & 1;
    int R = mh * 128 + row, b = R >> 4, c = R & 15;
    {
        const float* sp = ES + ((size_t)(b * H_ + h) * NC_ + c) * 64 + half * 32;
        short8* SaV = (short8*)Sa;
#pragma unroll
        for (int gg = 0; gg < 4; ++gg) {
            float4 f0 = *(const float4*)(sp + gg * 8);
            float4 f1 = *(const float4*)(sp + gg * 8 + 4);
            short8 s;
            s[0] = f2bf(f0.x); s[1] = f2bf(f0.y); s[2] = f2bf(f0.z); s[3] = f2bf(f0.w);
            s[4] = f2bf(f1.x); s[5] = f2bf(f1.y); s[6] = f2bf(f1.z); s[7] = f2bf(f1.w);
            SaV[(half * 4 + gg) * 128 + row] = s;
        }
    }
    __syncthreads();
    int lane = tid & 63, wave = tid >> 6;
    int wm = wave >> 1, wn = wave & 1;
    int lrow = lane & 15, lk = lane >> 4;
    const short8* SaF = (const short8*)Sa;
    const short8* VbF = (const short8*)Vb;
    f32x4 acc[4][4] = {};
#pragma unroll
    for (int ks = 0; ks < 2; ++ks) {
        int g = ks * 4 + lk;
        short8 af[4], bf[4];
#pragma unroll
        for (int m = 0; m < 4; ++m)
            af[m] = SaF[g * 128 + wm * 64 + m * 16 + lrow];
#pragma unroll
        for (int n = 0; n < 4; ++n)
            bf[n] = VbF[g * 128 + wn * 64 + n * 16 + lrow];
#pragma unroll
        for (int m = 0; m < 4; ++m)
#pragma unroll
            for (int n = 0; n < 4; ++n)
                acc[m][n] = __builtin_amdgcn_mfma_f32_16x16x32_bf16(
                    af[m], bf[n], acc[m][n], 0, 0, 0);
    }
    __syncthreads();   // Sa/Vb reads done -> reuse as Ys

#pragma unroll
    for (int nf = 0; nf < 4; ++nf) {
        int l = wn * 64 + nf * 16 + lrow;
#pragma unroll
        for (int mf = 0; mf < 4; ++mf) {
            int rb = wm * 64 + mf * 16 + lk * 4;
#pragma unroll
            for (int r = 0; r < 4; ++r)
                Ys[(rb + r) * 128 + l] = f2bf(acc[mf][nf][r]);
        }
    }
    __syncthreads();

    const short8* YsV = (const short8*)Ys;
#pragma unroll
    for (int it = 0; it < 8; ++it) {
        int sidx = it * 256 + tid;          // 0..2047
        int rr = sidx >> 4;                 // local row 0..127
        int colq = sidx & 15;
        int Rr = mh * 128 + rr, bb = Rr >> 4, cc = Rr & 15;
        size_t gaddr = ((size_t)(bb * H_ + h)) * L_ + (size_t)cc * LC_ + colq * 8;
        short8 yv = *(const short8*)(Ybuf + gaddr);
        short8 cv = YsV[sidx];
        short8 o;
#pragma unroll
        for (int j = 0; j < 8; ++j) {
            float y = bf2f((unsigned short)yv[j]) + bf2f((unsigned short)cv[j]);
            o[j] = f2bf(0.5f * y * (1.0f + erff(y * 0.70710678118654752f)));
        }
        *(short8*)(gbf + gaddr) = o;
    }
}

// ---------------------------------------------------------------------------
// bf16 MFMA GEMM v5+T5 (8 waves / 512 thr / 128x128 tile, dbuf LDS, one
// barrier per K-step, s_setprio(1) around MFMA clusters).
// Grid dim3(M/128,N/128): XCD = row-panel%8 -> A-panel L2 locality.
// ---------------------------------------------------------------------------
template<bool TANH, bool OUTBF>
__global__ void __launch_bounds__(512)
gemm_mfma(const short* __restrict__ A, const short* __restrict__ Bt,
          const float* __restrict__ bias, void* __restrict__ Cout,
          int M, int N, int K) {
    __shared__ short As[2][128 * 36];
    __shared__ short Bs[2][128 * 36];
    int tid  = threadIdx.x;
    int lane = tid & 63;
    int wave = tid >> 6;                 // 0..7
    int wm = wave >> 2, wn = wave & 3;   // 2M x 4N
    int lrow = lane & 15, kblk = lane >> 4;
    int row0 = blockIdx.x * 128, col0 = blockIdx.y * 128;

    int srow = tid >> 2;            // 0..127
    int sk   = (tid & 3) * 8;       // k offset (shorts)
    const short* Ag = A  + (size_t)(row0 + srow) * K + sk;
    const short* Bg = Bt + (size_t)(col0 + srow) * K + sk;
    int si = srow * 36 + sk;

    f32x4 acc[4][2] = {};
    const int NT = K >> 5;          // 64 (GEMM1) / 32 (GEMM2) — even

    short8 pa = *(const short8*)(Ag),      pb = *(const short8*)(Bg);
    *(short8*)&As[0][si] = pa;
    *(short8*)&Bs[0][si] = pb;
    short8 qa = *(const short8*)(Ag + 32), qb = *(const short8*)(Bg + 32);
    __syncthreads();

    for (int t = 0; t < NT; t += 2) {
        if (t + 2 < NT) {
            int ko = (t + 2) << 5;
            pa = *(const short8*)(Ag + ko);
            pb = *(const short8*)(Bg + ko);
        }
        {
            short8 af[4], bf[2];
#pragma unroll
            for (int m = 0; m < 4; ++m)
                af[m] = *(const short8*)&As[0][(wm * 64 + m * 16 + lrow) * 36 + kblk * 8];
#pragma unroll
            for (int n = 0; n < 2; ++n)
                bf[n] = *(const short8*)&Bs[0][(wn * 32 + n * 16 + lrow) * 36 + kblk * 8];
            __builtin_amdgcn_s_setprio(1);
#pragma unroll
            for (int m = 0; m < 4; ++m)
#pragma unroll
                for (int n = 0; n < 2; ++n)
                    acc[m][n] = __builtin_amdgcn_mfma_f32_16x16x32_bf16(
                        af[m], bf[n], acc[m][n], 0, 0, 0);
            __builtin_amdgcn_s_setprio(0);
        }
        *(short8*)&As[1][si] = qa;
        *(short8*)&Bs[1][si] = qb;
        __syncthreads();

        if (t + 3 < NT) {
            int ko = (t + 3) << 5;
            qa = *(const short8*)(Ag + ko);
            qb = *(const short8*)(Bg + ko);
        }
        {
            short8 af[4], bf[2];
#pragma unroll
            for (int m = 0; m < 4; ++m)
                af[m] = *(const short8*)&As[1][(wm * 64 + m * 16 + lrow) * 36 + kblk * 8];
#pragma unroll
            for (int n = 0; n < 2; ++n)
                bf[n] = *(const short8*)&Bs[1][(wn * 32 + n * 16 + lrow) * 36 + kblk * 8];
            __builtin_amdgcn_s_setprio(1);
#pragma unroll
            for (int m = 0; m < 4; ++m)
#pragma unroll
                for (int n = 0; n < 2; ++n)
                    acc[m][n] = __builtin_amdgcn_mfma_f32_16x16x32_bf16(
                        af[m], bf[n], acc[m][n], 0, 0, 0);
            __builtin_amdgcn_s_setprio(0);
        }
        if (t + 2 < NT) {
            *(short8*)&As[0][si] = pa;
            *(short8*)&Bs[0][si] = pb;
        }
        __syncthreads();
    }

    // epilogue: C/D layout col=lane&15, row=(lane>>4)*4+reg
#pragma unroll
    for (int n = 0; n < 2; ++n) {
        int col = col0 + wn * 32 + n * 16 + lrow;
        float bb = bias[col];
#pragma unroll
        for (int m = 0; m < 4; ++m) {
            int rowb = row0 + wm * 64 + m * 16 + kblk * 4;
#pragma unroll
            for (int r = 0; r < 4; ++r) {
                float v = acc[m][n][r] + bb;
                if (TANH) v = tanhf(v);
                if (OUTBF) ((short*)Cout)[(size_t)(rowb + r) * N + col] = f2bf(v);
                else       ((float*)Cout)[(size_t)(rowb + r) * N + col] = v;
            }
        }
    }
}

// ---------------------------------------------------------------------------
extern "C" void kernel_launch(void* const* d_in, const int* in_sizes, int n_in,
                              void* d_out, int out_size, void* d_ws, size_t ws_size,
                              hipStream_t stream) {
    const float* u     = (const float*)d_in[0];
    const float* D     = (const float*)d_in[1];
    const float* logdt = (const float*)d_in[2];
    const float* C_re  = (const float*)d_in[3];
    const float* C_im  = (const float*)d_in[4];
    const float* W1    = (const float*)d_in[5];
    const float* b1    = (const float*)d_in[6];
    const float* W2    = (const float*)d_in[7];
    const float* b2    = (const float*)d_in[8];
    float* out = (float*)d_out;

    char* p = (char*)d_ws;
    float4* tab = (float4*)p;            p += 262144;      // H*N2*16
    char* regionA = p;                   p += 33554432;    // POW+ktab, later Ybuf
    float2* POW  = (float2*)regionA;                       // 512*129*32*8
    float*  ktab = (float*)(regionA + 16908288);           // 512*128*4
    short*  Ybuf = (short*)regionA;                        // B*H*L*2 = 32 MB (b,h,l)
    short* Psw = (short*)p;              p += 25165824;    // 512*192*128*2
    short* Vsw = (short*)p;              p += 8388608;     // 512*128*64*2
    float* E   = (float*)p;              p += 33554432;    // 8192*16*64*4
    short* gbf = (short*)p;              p += 33554432;    // B*H*L*2
    short* tb  = (short*)p;              p += 16777216;    // 8192*1024*2
    short* w1t = (short*)p;              p += 4194304;
    short* w2t = (short*)p;

    prolog <<<10880, 256, 0, stream>>>(logdt, C_re, C_im, W1, W2,
                                       tab, POW, w1t, w2t);
    t_ktab <<<H_ * 128 / 256, 256, 0, stream>>>(tab, POW, D, ktab);
    t1_fill<<<H_ * 320 * 8 / 256, 256, 0, stream>>>(tab, POW, ktab, Psw, Vsw);

    conv_mfma  <<<H_, 512, 0, stream>>>(u, Psw, E, Ybuf);
    k2_scan    <<<B_ * H_ * N2_ / 256, 256, 0, stream>>>(logdt, (float2*)E);
    dcarry_mfma<<<dim3(H_, 2), 256, 0, stream>>>(E, Vsw, Ybuf, gbf);

    gemm_mfma<true, true ><<<dim3(B_ * H_ / 128, 2 * H_ / 128), 512, 0, stream>>>(
        gbf, w1t, b1, tb, B_ * H_, 2 * H_, L_);
    gemm_mfma<false, false><<<dim3(B_ * H_ / 128, H_ / 128), 512, 0, stream>>>(
        tb, w2t, b2, out, B_ * H_, H_, 2 * H_);
}